// Round 10
// baseline (210.812 us; speedup 1.0000x reference)
//
#include <hip/hip_runtime.h>
#include <hip/hip_bf16.h>

// MHA forward, MI355X/gfx950.
// cast->bf16, fused QKV proj (MFMA NT-GEMM BK=64, Q cols pre-scaled), causal
// flash attention (128-row q-tiles, 8 waves, exact-balance grid, T14 prefetch),
// out proj (BM=64 tiles -> 512 blocks @ 2/CU).

#define DEVI __device__ __forceinline__

typedef __attribute__((ext_vector_type(4))) float f32x4;
typedef __attribute__((ext_vector_type(8))) short s16x8;

static constexpr int SEQ = 2048;
static constexpr int DM  = 1024;
static constexpr int NH  = 16;
static constexpr int HD  = 64;
static constexpr int LDQKV = 3072;   // fused QKV row stride

DEVI short f2bf(float f) {
  __hip_bfloat16 h = __float2bfloat16(f);
  return *(short*)&h;
}

// ---------------- fp32 -> bf16 casts ----------------
__global__ void cast_kernel(const float* __restrict__ in, short* __restrict__ out, int n4) {
  int i = blockIdx.x * blockDim.x + threadIdx.x;
  if (i >= n4) return;
  float4 v = ((const float4*)in)[i];
  short4 o;
  o.x = f2bf(v.x); o.y = f2bf(v.y); o.z = f2bf(v.z); o.w = f2bf(v.w);
  ((short4*)out)[i] = o;
}

// 4 weight matrices, 1M floats (256K float4) each. seg = blockIdx>>10.
__global__ void cast4_kernel(const float* __restrict__ w0, const float* __restrict__ w1,
                             const float* __restrict__ w2, const float* __restrict__ w3,
                             short* __restrict__ o012, short* __restrict__ o3) {
  int seg = blockIdx.x >> 10;
  int i = (blockIdx.x & 1023) * blockDim.x + threadIdx.x;   // 0..256K-1 (float4 idx)
  const float* src = (seg == 0) ? w0 : (seg == 1) ? w1 : (seg == 2) ? w2 : w3;
  short* dst = (seg == 3) ? o3 : (o012 + (size_t)seg * (1u << 20));
  float4 v = ((const float4*)src)[i];
  short4 o;
  o.x = f2bf(v.x); o.y = f2bf(v.y); o.z = f2bf(v.z); o.w = f2bf(v.w);
  ((short4*)dst)[i] = o;
}

// ---------------- NT GEMM: C[m][n] = sum_k A[m][k]*B[n][k] ----------------
// A: M x K bf16 row-major, B: N x K bf16 row-major. BM x 128 tile, BK=64
// (half the barrier drains of BK=32), 4 waves.
//   BM=128: wave grid 2x2, wave tile 64x64, acc 4x4  (QKV proj, 768 blocks)
//   BM=64 : wave grid 1x4, wave tile 64x32, acc 4x2  (out proj, 512 blocks @2/CU)
// m97 staging: global_load_lds width-16, 2 barriers/K-step.
// Columns < qcols scaled by qscale in epilogue (folds softmax scale into Q).
template<int BM, bool BF16_OUT>
__global__ __launch_bounds__(256) void gemm_nt(const short* __restrict__ A,
                                               const short* __restrict__ Bm,
                                               void* __restrict__ Cv,
                                               int M, int N, int K,
                                               int qcols, float qscale) {
  __shared__ short As[BM * 64];
  __shared__ short Bs[128 * 64];
  constexpr int WCN = (BM == 128) ? 2 : 4;   // waves along N
  constexpr int WTN = 128 / WCN;             // wave tile N: 64 or 32
  constexpr int FC  = WTN / 16;              // 4 or 2 col frags
  const int t = threadIdx.x;
  const int l = t & 63;
  const int w = t >> 6;
  const int wr = (BM == 128) ? (w >> 1) : 0;
  const int wc = (BM == 128) ? (w & 1) : w;
  const int lr = l & 15, lg = l >> 4;
  const int m0 = blockIdx.y * BM, n0 = blockIdx.x * 128;
  f32x4 acc[4][FC] = {};

  for (int k0 = 0; k0 < K; k0 += 64) {
    __syncthreads();  // previous iteration's LDS reads done
#pragma unroll
    for (int i = 0; i < BM / 32; ++i) {      // stage A: BM x 64
      int idx = t * 8 + i * 2048;
      int row = idx >> 6, col = idx & 63;
      __builtin_amdgcn_global_load_lds(
          (const __attribute__((address_space(1))) void*)(A + (size_t)(m0 + row) * K + k0 + col),
          (__attribute__((address_space(3))) void*)(As + idx), 16, 0, 0);
    }
#pragma unroll
    for (int i = 0; i < 4; ++i) {            // stage B: 128 x 64
      int idx = t * 8 + i * 2048;
      int row = idx >> 6, col = idx & 63;
      __builtin_amdgcn_global_load_lds(
          (const __attribute__((address_space(1))) void*)(Bm + (size_t)(n0 + row) * K + k0 + col),
          (__attribute__((address_space(3))) void*)(Bs + idx), 16, 0, 0);
    }
    __syncthreads();  // staged (compiler drains vmcnt before barrier)

#pragma unroll
    for (int kk = 0; kk < 2; ++kk) {
      s16x8 af[4], bfr[FC];
#pragma unroll
      for (int i = 0; i < 4; ++i)
        af[i] = *(const s16x8*)&As[(wr * 64 + i * 16 + lr) * 64 + kk * 32 + lg * 8];
#pragma unroll
      for (int j = 0; j < FC; ++j)
        bfr[j] = *(const s16x8*)&Bs[(wc * WTN + j * 16 + lr) * 64 + kk * 32 + lg * 8];
#pragma unroll
      for (int i = 0; i < 4; ++i)
#pragma unroll
        for (int j = 0; j < FC; ++j)
          acc[i][j] = __builtin_amdgcn_mfma_f32_16x16x32_bf16(af[i], bfr[j], acc[i][j], 0, 0, 0);
    }
  }

  const float s = (n0 < qcols) ? qscale : 1.0f;
  // epilogue: D[row=(l>>4)*4+r][col=l&15] per frag
#pragma unroll
  for (int i = 0; i < 4; ++i)
#pragma unroll
    for (int j = 0; j < FC; ++j)
#pragma unroll
      for (int r = 0; r < 4; ++r) {
        int row = m0 + wr * 64 + i * 16 + lg * 4 + r;
        int col = n0 + wc * WTN + j * 16 + lr;
        if constexpr (BF16_OUT)
          ((short*)Cv)[(size_t)row * N + col] = f2bf(acc[i][j][r] * s);
        else
          ((float*)Cv)[(size_t)row * N + col] = acc[i][j][r] * s;
      }
}

// ---------------- causal flash attention ----------------
// QKV: [B*S, 3072] bf16 (Q pre-scaled by 1/sqrt(hd)*log2(e); K at +1024, V at +2048).
// O: [B*S, 1024] bf16.
// 128-row q-tiles, 8 waves x 16 q-rows, 512 threads. 512 blocks @ 2/CU:
// one K/V staging + 2 barriers serve 128 q-rows (per-CU tile iterations 66->34).
// Exact balance: bh = bid&31 (fast), g=(bid>>5)&7, rr=(bid>>8)&1, qt = rr?15-g:g
// -> each CU's 2 co-resident blocks total exactly 34 kv-tiles. (bh,qt) bijective.
// T14 async-stage prefetch: barrier A = __syncthreads (vmcnt drain only waits the
// regs consumed right below); barrier B = raw s_barrier + lgkmcnt(0) so the next
// tile's prefetch stays in flight.
__global__ __launch_bounds__(512) void attn_kernel(const unsigned short* __restrict__ QKV,
                                                   unsigned short* __restrict__ O) {
  __shared__ short Ks[64 * 72];
  __shared__ short Vt[64 * 72];    // transposed: Vt[d][kv]
  __shared__ short Ps[128 * 72];

  const int t = threadIdx.x, l = t & 63, w = t >> 6;   // w: 0..7
  const int lr = l & 15, lg = l >> 4;
  const int bid = blockIdx.x;
  const int bh = bid & 31;              // fast dim: b*NH+h
  const int g  = (bid >> 5) & 7;
  const int rr = (bid >> 8) & 1;
  const int qt = rr ? 15 - g : g;       // q-tile 0..15 (128 rows each)
  const int b = bh >> 4, h = bh & 15;
  const int q0 = qt * 128;
  const int ktmax = 2 * qt + 1;         // kv tiles 0..ktmax
  const size_t rowbase = (size_t)b * SEQ * LDQKV;
  const int cb = h * HD;
  const unsigned short* Q = QKV + cb;
  const unsigned short* K = QKV + DM + cb;
  const unsigned short* V = QKV + 2 * DM + cb;

  // Q fragments: rows q0 + w*16 + lr, k-slices lg*8 (+32)
  s16x8 qf[2];
  {
    const unsigned short* qp = Q + rowbase + (size_t)(q0 + w * 16 + lr) * LDQKV + lg * 8;
    qf[0] = *(const s16x8*)(qp);
    qf[1] = *(const s16x8*)(qp + 32);
  }

  f32x4 acc[4] = {};
  float mrun[4], lrun[4];   // lrun: per-lane partials (reduced in epilogue)
#pragma unroll
  for (int r = 0; r < 4; ++r) { mrun[r] = -3.0e38f; lrun[r] = 0.f; }

  // staging map: kv row = l, d-slice = w*8 (8 elems/thread for K and V each)
  s16x8 kA, vA;
  {
    const unsigned short* kp = K + rowbase + (size_t)l * LDQKV + w * 8;
    kA = *(const s16x8*)kp;
    const unsigned short* vp = V + rowbase + (size_t)l * LDQKV + w * 8;
    vA = *(const s16x8*)vp;
  }

  for (int kt = 0; kt <= ktmax; ++kt) {
    const int kv0 = kt * 64;
    // Barrier A: WAR + compiler fence (vmcnt drain = the regs we consume now)
    __syncthreads();

    // ---- write staged regs to LDS (K rows; V transposed)
    *(s16x8*)&Ks[l * 72 + w * 8] = kA;
#pragma unroll
    for (int jj = 0; jj < 8; ++jj) Vt[(w * 8 + jj) * 72 + l] = vA[jj];

    // ---- T14: prefetch next tile (clamped on last iter)
    {
      const int nkv = (kt < ktmax) ? kv0 + 64 : kv0;
      const unsigned short* kp = K + rowbase + (size_t)(nkv + l) * LDQKV + w * 8;
      kA = *(const s16x8*)kp;
      const unsigned short* vp = V + rowbase + (size_t)(nkv + l) * LDQKV + w * 8;
      vA = *(const s16x8*)vp;
    }

    // Barrier B: RAW — drain own LDS writes; vmcnt NOT drained (prefetch lives)
    asm volatile("s_waitcnt lgkmcnt(0)" ::: "memory");
    __builtin_amdgcn_s_barrier();

    // ---- S = Q K^T
    f32x4 sc[4] = {};
    __builtin_amdgcn_s_setprio(1);
#pragma unroll
    for (int dk = 0; dk < 2; ++dk)
#pragma unroll
      for (int j = 0; j < 4; ++j) {
        s16x8 kb = *(const s16x8*)&Ks[(j * 16 + lr) * 72 + dk * 32 + lg * 8];
        sc[j] = __builtin_amdgcn_mfma_f32_16x16x32_bf16(qf[dk], kb, sc[j], 0, 0, 0);
      }
    __builtin_amdgcn_s_setprio(0);

    // ---- causal mask: only when this wave's rows intersect the diagonal
    if (kv0 + 63 > q0 + w * 16) {
#pragma unroll
      for (int j = 0; j < 4; ++j)
#pragma unroll
        for (int r = 0; r < 4; ++r) {
          int kg = kv0 + j * 16 + lr;
          int qg = q0 + w * 16 + lg * 4 + r;
          if (kg > qg) sc[j][r] = -3.0e38f;
        }
    }

    // ---- per-lane local maxima; full reduce + rescale only on demand (T13)
    float lmax[4];
#pragma unroll
    for (int r = 0; r < 4; ++r)
      lmax[r] = fmaxf(fmaxf(sc[0][r], sc[1][r]), fmaxf(sc[2][r], sc[3][r]));
    bool need = false;
#pragma unroll
    for (int r = 0; r < 4; ++r) need |= (lmax[r] > mrun[r] + 8.0f);
    if (__any(need)) {
#pragma unroll
      for (int r = 0; r < 4; ++r) {
        float m = lmax[r];
#pragma unroll
        for (int mk = 1; mk < 16; mk <<= 1) m = fmaxf(m, __shfl_xor(m, mk, 64));
        float mnew = fmaxf(mrun[r], m);
        float corr = exp2f(mrun[r] - mnew);
        mrun[r] = mnew;
        lrun[r] *= corr;
#pragma unroll
        for (int j = 0; j < 4; ++j) acc[j][r] *= corr;
      }
    }

    // ---- P = exp2(S - mrun); per-lane row-sum partials
#pragma unroll
    for (int r = 0; r < 4; ++r) {
      float rsum = 0.f;
#pragma unroll
      for (int j = 0; j < 4; ++j) {
        float p = exp2f(sc[j][r] - mrun[r]);
        sc[j][r] = p;
        rsum += p;
      }
      lrun[r] += rsum;
    }

    // ---- P -> LDS (intra-wave; wave w touches only rows [w*16, w*16+16))
#pragma unroll
    for (int j = 0; j < 4; ++j)
#pragma unroll
      for (int r = 0; r < 4; ++r)
        Ps[(w * 16 + lg * 4 + r) * 72 + j * 16 + lr] = f2bf(sc[j][r]);

    // ---- O += P @ V
    __builtin_amdgcn_s_setprio(1);
#pragma unroll
    for (int ks = 0; ks < 2; ++ks) {
      s16x8 pa = *(const s16x8*)&Ps[(w * 16 + lr) * 72 + ks * 32 + lg * 8];
#pragma unroll
      for (int j = 0; j < 4; ++j) {
        s16x8 vb = *(const s16x8*)&Vt[(j * 16 + lr) * 72 + ks * 32 + lg * 8];
        acc[j] = __builtin_amdgcn_mfma_f32_16x16x32_bf16(pa, vb, acc[j], 0, 0, 0);
      }
    }
    __builtin_amdgcn_s_setprio(0);
  }

  // ---- epilogue: reduce lrun across the 16 row-lanes, then O[q][d] = acc/lsum
#pragma unroll
  for (int r = 0; r < 4; ++r) {
    float ls = lrun[r];
#pragma unroll
    for (int mk = 1; mk < 16; mk <<= 1) ls += __shfl_xor(ls, mk, 64);
    lrun[r] = ls;
  }
#pragma unroll
  for (int j = 0; j < 4; ++j)
#pragma unroll
    for (int r = 0; r < 4; ++r) {
      int qg = q0 + w * 16 + lg * 4 + r;
      float o = acc[j][r] / lrun[r];
      O[(size_t)b * SEQ * DM + (size_t)qg * DM + cb + j * 16 + lr] = (unsigned short)f2bf(o);
    }
}

// ---------------- launch ----------------
extern "C" void kernel_launch(void* const* d_in, const int* in_sizes, int n_in,
                              void* d_out, int out_size, void* d_ws, size_t ws_size,
                              hipStream_t stream) {
  const float* x  = (const float*)d_in[0];
  const float* wq = (const float*)d_in[1];
  const float* wk = (const float*)d_in[2];
  const float* wv = (const float*)d_in[3];
  const float* wo = (const float*)d_in[4];
  float* out = (float*)d_out;

  short* ws   = (short*)d_ws;
  short* xb   = ws;                     // 4M elems  [4096,1024]
  short* wqkv = xb   + (4u << 20);      // 3M elems  [3072,1024] (wq;wk;wv)
  short* wob  = wqkv + (3u << 20);      // 1M elems  [1024,1024]
  short* QKV  = wob  + (1u << 20);      // 12M elems [4096,3072]
  short* Om   = QKV  + (12u << 20);     // 4M elems  [4096,1024]
  // total 24M shorts = 48 MB

  cast_kernel<<<4096, 256, 0, stream>>>(x, xb, 1 << 20);
  cast4_kernel<<<4096, 256, 0, stream>>>(wq, wk, wv, wo, wqkv, wob);

  // fused QKV projection; Q columns pre-scaled by 1/sqrt(hd)*log2(e)
  const float SCL = 0.125f * 1.4426950408889634f;
  gemm_nt<128, true><<<dim3(24, 32), 256, 0, stream>>>(xb, wqkv, QKV, 4096, LDQKV, 1024,
                                                       DM, SCL);

  // exact-balance 1D grid, 128-row q-tiles
  attn_kernel<<<512, 512, 0, stream>>>((const unsigned short*)QKV,
                                       (unsigned short*)Om);

  // output projection: BM=64 tiles -> 512 blocks @ 2/CU
  gemm_nt<64, false><<<dim3(8, 64), 256, 0, stream>>>(Om, wob, out, 4096, 1024, 1024,
                                                      0, 1.0f);
}